// Round 7
// baseline (209.641 us; speedup 1.0000x reference)
//
#include <hip/hip_runtime.h>

// MultiHashEncoding: 2-level dense grid trilinear interpolation, spatially
// binned for L2 locality.
//
// Round 5/6 evidence: two very different kernels (VALU 50% vs 12%) both hit
// ~180us with identical FETCH_SIZE (583MB) -> random-64B-granule fabric/LLC
// ceiling (~3.2 TB/s). Fix: bin points by coarse spatial cell so concurrent
// points share emb lines (per-XCD L2 resident), then scatter output rows.
//
// Reference semantics (bit-exact corners): corner = floor(coords + OFFSET)
// with f32 add BEFORE floor; clip to [0,dim-1]; weight from CLIPPED corner.
// Weight factorization is separable (rounding diff ~1e-7 << 8.1e-2 threshold).

typedef float floatx4 __attribute__((ext_vector_type(4)));

#define KXB 8
#define KYB 17
#define KZB 31
#define NBINS (KXB * KYB * KZB)          // 4216
#define SCAN_T 256
#define CHUNK ((NBINS + SCAN_T - 1) / SCAN_T)  // 17

__device__ __forceinline__ int point_key(float px, float py, float pz) {
    int ix = (int)(px * 15.0f);  ix = min(max(ix, 0), 15);
    int iy = (int)(py * 135.0f); iy = min(max(iy, 0), 135);
    int iz = (int)(pz * 240.0f); iz = min(max(iz, 0), 240);
    return ((ix >> 1) * KYB + (iy >> 3)) * KZB + (iz >> 3);
}

// ---------------- pass 1: keys + histogram ----------------
__global__ __launch_bounds__(256)
void k_hist(const float* __restrict__ pts, int n,
            unsigned* __restrict__ keys, unsigned* __restrict__ hist) {
    const int i = blockIdx.x * blockDim.x + threadIdx.x;
    if (i >= n) return;
    const size_t b = (size_t)i * 3;
    const int key = point_key(pts[b], pts[b + 1], pts[b + 2]);
    keys[i] = (unsigned)key;
    atomicAdd(&hist[key], 1u);
}

// ---------------- pass 2: exclusive scan (one block) ----------------
__global__ __launch_bounds__(SCAN_T)
void k_scan(const unsigned* __restrict__ hist, unsigned* __restrict__ cursor) {
    __shared__ unsigned part[SCAN_T];
    const int t = threadIdx.x;
    unsigned local[CHUNK];
    unsigned s = 0;
#pragma unroll
    for (int j = 0; j < CHUNK; ++j) {
        const int idx = t * CHUNK + j;
        const unsigned v = (idx < NBINS) ? hist[idx] : 0u;
        local[j] = s;          // exclusive within chunk
        s += v;
    }
    part[t] = s;
    __syncthreads();
    // inclusive Hillis-Steele scan of chunk sums
    for (int off = 1; off < SCAN_T; off <<= 1) {
        unsigned y = 0;
        if (t >= off) y = part[t - off];
        __syncthreads();
        if (t >= off) part[t] += y;
        __syncthreads();
    }
    const unsigned base = part[t] - s;   // exclusive chunk base
#pragma unroll
    for (int j = 0; j < CHUNK; ++j) {
        const int idx = t * CHUNK + j;
        if (idx < NBINS) cursor[idx] = base + local[j];
    }
}

// ---------------- pass 3: scatter coords + orig index ----------------
__global__ __launch_bounds__(256)
void k_scatter(const float* __restrict__ pts, int n,
               const unsigned* __restrict__ keys, unsigned* __restrict__ cursor,
               floatx4* __restrict__ sorted) {
    const int i = blockIdx.x * blockDim.x + threadIdx.x;
    if (i >= n) return;
    const size_t b = (size_t)i * 3;
    const unsigned pos = atomicAdd(&cursor[keys[i]], 1u);
    floatx4 r = { pts[b], pts[b + 1], pts[b + 2], __int_as_float(i) };
    sorted[pos] = r;
}

// ---------------- main compute ----------------
template<int T, int H, int W>
__device__ __forceinline__ void level_setup(float px, float py, float pz, int dbase,
                                            int* __restrict__ off,   // [8]
                                            float* __restrict__ w) { // [8]
    const float cx = px * (float)(T - 1);
    const float cy = py * (float)(H - 1);
    const float cz = pz * (float)(W - 1);
    float gx[2] = { floorf(cx), floorf(cx + 1.0f) };
    float gy[2] = { floorf(cy), floorf(cy + 1.0f) };
    float gz[2] = { floorf(cz), floorf(cz + 1.0f) };
    float wx[2], wy[2], wz[2];
    int   xo[2], yo[2], zo[2];
#pragma unroll
    for (int b = 0; b < 2; ++b) {
        gx[b] = fminf(fmaxf(gx[b], 0.0f), (float)(T - 1));
        gy[b] = fminf(fmaxf(gy[b], 0.0f), (float)(H - 1));
        gz[b] = fminf(fmaxf(gz[b], 0.0f), (float)(W - 1));
        wx[b] = 1.0f - fabsf(gx[b] - cx);
        wy[b] = 1.0f - fabsf(gy[b] - cy);
        wz[b] = 1.0f - fabsf(gz[b] - cz);
        xo[b] = (int)gx[b] * (H * W * 16);
        yo[b] = (int)gy[b] * (W * 16);
        zo[b] = (int)gz[b] * 16 + dbase;
    }
    float wyz[4];
    int   yzo[4];
#pragma unroll
    for (int j = 0; j < 2; ++j)
#pragma unroll
        for (int k = 0; k < 2; ++k) {
            wyz[2 * j + k] = wy[j] * wz[k];
            yzo[2 * j + k] = yo[j] + zo[k];
        }
#pragma unroll
    for (int c = 0; c < 8; ++c) {
        const int i = (c >> 2) & 1, jk = c & 3;
        w[c]   = wx[i] * wyz[jk];
        off[c] = xo[i] + yzo[jk];
    }
}

__device__ __forceinline__ void encode_point(float px, float py, float pz, int d,
                                             const float* __restrict__ emb0,
                                             const float* __restrict__ emb1,
                                             float* __restrict__ row) {
    int   o0[8], o1[8];
    float w0[8], w1[8];
    level_setup<16, 136, 241>(px, py, pz, d, o0, w0);
    level_setup<9, 69, 121>(px, py, pz, d, o1, w1);

    floatx4 v0[8], v1[8];
#pragma unroll
    for (int c = 0; c < 8; ++c) v0[c] = *(const floatx4*)(emb0 + o0[c]);
#pragma unroll
    for (int c = 0; c < 8; ++c) v1[c] = *(const floatx4*)(emb1 + o1[c]);

    floatx4 a0 = {0.f, 0.f, 0.f, 0.f}, a1 = {0.f, 0.f, 0.f, 0.f};
#pragma unroll
    for (int c = 0; c < 8; ++c) {
        a0 += w0[c] * v0[c];
        a1 += w1[c] * v1[c];
    }
    __builtin_nontemporal_store(a0, (floatx4*)(row + d));
    __builtin_nontemporal_store(a1, (floatx4*)(row + 16 + d));
}

// sorted variant: 4 lanes = 1 point; blocks XCD-swizzled so each XCD works a
// contiguous (spatially compact) slice of the sorted order.
__global__ __launch_bounds__(256)
void k_main_sorted(const floatx4* __restrict__ sorted,
                   const float* __restrict__ emb0,
                   const float* __restrict__ emb1,
                   float* __restrict__ out, int n) {
    // bijective XCD swizzle (m204 form), NXCD=8
    const int nwg = gridDim.x;
    const int q = nwg >> 3, r = nwg & 7;
    const int xcd = blockIdx.x & 7, i = blockIdx.x >> 3;
    const int wg = (xcd < r ? xcd * (q + 1) : r * (q + 1) + (xcd - r) * q) + i;

    const int g = wg * blockDim.x + threadIdx.x;
    const int sp = g >> 2;
    const int d = (g & 3) * 4;
    if (sp >= n) return;

    const floatx4 pc = sorted[sp];
    const int orig = __float_as_int(pc.w);
    encode_point(pc.x, pc.y, pc.z, d, emb0, emb1, out + (size_t)orig * 32);
}

// fallback (no workspace): round-6 behavior
__global__ __launch_bounds__(256)
void k_main_plain(const float* __restrict__ pts,
                  const float* __restrict__ emb0,
                  const float* __restrict__ emb1,
                  float* __restrict__ out, int n) {
    const int g = blockIdx.x * blockDim.x + threadIdx.x;
    const int p = g >> 2;
    const int d = (g & 3) * 4;
    if (p >= n) return;
    const size_t b = (size_t)p * 3;
    encode_point(pts[b], pts[b + 1], pts[b + 2], d, emb0, emb1,
                 out + (size_t)p * 32);
}

extern "C" void kernel_launch(void* const* d_in, const int* in_sizes, int n_in,
                              void* d_out, int out_size, void* d_ws, size_t ws_size,
                              hipStream_t stream) {
    const float* pts  = (const float*)d_in[0];
    const float* emb0 = (const float*)d_in[1];
    const float* emb1 = (const float*)d_in[2];
    float* out = (float*)d_out;
    const int n = in_sizes[0] / 3;

    const int block = 256;
    const int grid_pt  = (n + block - 1) / block;                    // 1 thread/pt
    const int grid_4pt = (int)(((long long)n * 4 + block - 1) / block); // 4 lanes/pt

    // workspace layout
    const size_t off_keys   = 0;
    const size_t off_sorted = ((size_t)n * 4 + 15) & ~(size_t)15;
    const size_t off_hist   = off_sorted + (size_t)n * 16;
    const size_t off_cursor = off_hist + (size_t)NBINS * 4;
    const size_t need       = off_cursor + (size_t)NBINS * 4;

    if (ws_size < need) {
        k_main_plain<<<grid_4pt, block, 0, stream>>>(pts, emb0, emb1, out, n);
        return;
    }

    char* ws = (char*)d_ws;
    unsigned* keys   = (unsigned*)(ws + off_keys);
    floatx4*  sorted = (floatx4*)(ws + off_sorted);
    unsigned* hist   = (unsigned*)(ws + off_hist);
    unsigned* cursor = (unsigned*)(ws + off_cursor);

    hipMemsetAsync(hist, 0, (size_t)NBINS * 4, stream);
    k_hist<<<grid_pt, block, 0, stream>>>(pts, n, keys, hist);
    k_scan<<<1, SCAN_T, 0, stream>>>(hist, cursor);
    k_scatter<<<grid_pt, block, 0, stream>>>(pts, n, keys, cursor, sorted);
    k_main_sorted<<<grid_4pt, block, 0, stream>>>(sorted, emb0, emb1, out, n);
}

// Round 8
// 149.007 us; speedup vs baseline: 1.4069x; 1.4069x over previous
//
#include <hip/hip_runtime.h>

// MultiHashEncoding: 2-level dense grid trilinear interpolation, spatially
// binned for L2 locality.
//
// r7 evidence: sorted main kernel FETCH 583->38MB (locality win), 98us, but
// VGPR=36 (compiler collapsed the gather batch) and preprocessing ~110us.
// r8: (1) sched_barrier pins 16 gathers in flight in main; (2) rank from the
// hist atomic -> atomic-free scatter; (3) 4-pt/thread vectorized hist/scatter.
//
// Reference semantics (bit-exact corners): corner = floor(coords + OFFSET)
// with f32 add BEFORE floor; clip to [0,dim-1]; weight from CLIPPED corner.

typedef float floatx4 __attribute__((ext_vector_type(4)));

#define KXB 8
#define KYB 17
#define KZB 31
#define NBINS (KXB * KYB * KZB)          // 4216
#define SCAN_T 256
#define CHUNK ((NBINS + SCAN_T - 1) / SCAN_T)  // 17

__device__ __forceinline__ int point_key(float px, float py, float pz) {
    int ix = (int)(px * 15.0f);  ix = min(max(ix, 0), 15);
    int iy = (int)(py * 135.0f); iy = min(max(iy, 0), 135);
    int iz = (int)(pz * 240.0f); iz = min(max(iz, 0), 240);
    return ((ix >> 1) * KYB + (iy >> 3)) * KZB + (iz >> 3);
}

__device__ __forceinline__ void load4pts(const float* __restrict__ pts, int i4,
                                         float px[4], float py[4], float pz[4]) {
    const floatx4* v = (const floatx4*)(pts + (size_t)i4 * 3);
    const floatx4 a = v[0], b = v[1], c = v[2];
    px[0] = a.x; py[0] = a.y; pz[0] = a.z;
    px[1] = a.w; py[1] = b.x; pz[1] = b.y;
    px[2] = b.z; py[2] = b.w; pz[2] = c.x;
    px[3] = c.y; py[3] = c.z; pz[3] = c.w;
}

// ---------------- pass 1: keys + rank (one atomic) ----------------
__global__ __launch_bounds__(256)
void k_hist(const float* __restrict__ pts, int n,
            unsigned* __restrict__ keys, unsigned* __restrict__ rank,
            unsigned* __restrict__ hist) {
    const int i4 = (blockIdx.x * blockDim.x + threadIdx.x) * 4;
    if (i4 >= n) return;
    if (i4 + 3 < n) {
        float px[4], py[4], pz[4];
        load4pts(pts, i4, px, py, pz);
        unsigned k[4], r[4];
#pragma unroll
        for (int j = 0; j < 4; ++j) {
            k[j] = (unsigned)point_key(px[j], py[j], pz[j]);
            r[j] = atomicAdd(&hist[k[j]], 1u);
        }
        *(uint4*)(keys + i4) = make_uint4(k[0], k[1], k[2], k[3]);
        *(uint4*)(rank + i4) = make_uint4(r[0], r[1], r[2], r[3]);
    } else {
        for (int j = 0; j < 4 && i4 + j < n; ++j) {
            const size_t b = (size_t)(i4 + j) * 3;
            const unsigned k = (unsigned)point_key(pts[b], pts[b+1], pts[b+2]);
            keys[i4 + j] = k;
            rank[i4 + j] = atomicAdd(&hist[k], 1u);
        }
    }
}

// ---------------- pass 2: exclusive scan (one block) ----------------
__global__ __launch_bounds__(SCAN_T)
void k_scan(const unsigned* __restrict__ hist, unsigned* __restrict__ base) {
    __shared__ unsigned part[SCAN_T];
    const int t = threadIdx.x;
    unsigned local[CHUNK];
    unsigned s = 0;
#pragma unroll
    for (int j = 0; j < CHUNK; ++j) {
        const int idx = t * CHUNK + j;
        const unsigned v = (idx < NBINS) ? hist[idx] : 0u;
        local[j] = s;
        s += v;
    }
    part[t] = s;
    __syncthreads();
    for (int off = 1; off < SCAN_T; off <<= 1) {
        unsigned y = 0;
        if (t >= off) y = part[t - off];
        __syncthreads();
        if (t >= off) part[t] += y;
        __syncthreads();
    }
    const unsigned b = part[t] - s;
#pragma unroll
    for (int j = 0; j < CHUNK; ++j) {
        const int idx = t * CHUNK + j;
        if (idx < NBINS) base[idx] = b + local[j];
    }
}

// ---------------- pass 3: atomic-free scatter ----------------
__global__ __launch_bounds__(256)
void k_scatter(const float* __restrict__ pts, int n,
               const unsigned* __restrict__ keys, const unsigned* __restrict__ rank,
               const unsigned* __restrict__ base, floatx4* __restrict__ sorted) {
    const int i4 = (blockIdx.x * blockDim.x + threadIdx.x) * 4;
    if (i4 >= n) return;
    if (i4 + 3 < n) {
        float px[4], py[4], pz[4];
        load4pts(pts, i4, px, py, pz);
        const uint4 k = *(const uint4*)(keys + i4);
        const uint4 r = *(const uint4*)(rank + i4);
        const unsigned kk[4] = { k.x, k.y, k.z, k.w };
        const unsigned rr[4] = { r.x, r.y, r.z, r.w };
#pragma unroll
        for (int j = 0; j < 4; ++j) {
            const unsigned pos = base[kk[j]] + rr[j];
            floatx4 rec = { px[j], py[j], pz[j], __int_as_float(i4 + j) };
            sorted[pos] = rec;
        }
    } else {
        for (int j = 0; j < 4 && i4 + j < n; ++j) {
            const size_t b = (size_t)(i4 + j) * 3;
            const unsigned pos = base[keys[i4 + j]] + rank[i4 + j];
            floatx4 rec = { pts[b], pts[b+1], pts[b+2], __int_as_float(i4 + j) };
            sorted[pos] = rec;
        }
    }
}

// ---------------- main compute ----------------
template<int T, int H, int W>
__device__ __forceinline__ void level_setup(float px, float py, float pz, int dbase,
                                            int* __restrict__ off,   // [8]
                                            float* __restrict__ w) { // [8]
    const float cx = px * (float)(T - 1);
    const float cy = py * (float)(H - 1);
    const float cz = pz * (float)(W - 1);
    float gx[2] = { floorf(cx), floorf(cx + 1.0f) };
    float gy[2] = { floorf(cy), floorf(cy + 1.0f) };
    float gz[2] = { floorf(cz), floorf(cz + 1.0f) };
    float wx[2], wy[2], wz[2];
    int   xo[2], yo[2], zo[2];
#pragma unroll
    for (int b = 0; b < 2; ++b) {
        gx[b] = fminf(fmaxf(gx[b], 0.0f), (float)(T - 1));
        gy[b] = fminf(fmaxf(gy[b], 0.0f), (float)(H - 1));
        gz[b] = fminf(fmaxf(gz[b], 0.0f), (float)(W - 1));
        wx[b] = 1.0f - fabsf(gx[b] - cx);
        wy[b] = 1.0f - fabsf(gy[b] - cy);
        wz[b] = 1.0f - fabsf(gz[b] - cz);
        xo[b] = (int)gx[b] * (H * W * 16);
        yo[b] = (int)gy[b] * (W * 16);
        zo[b] = (int)gz[b] * 16 + dbase;
    }
    float wyz[4];
    int   yzo[4];
#pragma unroll
    for (int j = 0; j < 2; ++j)
#pragma unroll
        for (int k = 0; k < 2; ++k) {
            wyz[2 * j + k] = wy[j] * wz[k];
            yzo[2 * j + k] = yo[j] + zo[k];
        }
#pragma unroll
    for (int c = 0; c < 8; ++c) {
        const int i = (c >> 2) & 1, jk = c & 3;
        w[c]   = wx[i] * wyz[jk];
        off[c] = xo[i] + yzo[jk];
    }
}

__device__ __forceinline__ void encode_point(float px, float py, float pz, int d,
                                             const float* __restrict__ emb0,
                                             const float* __restrict__ emb1,
                                             float* __restrict__ row) {
    int   o0[8], o1[8];
    float w0[8], w1[8];
    level_setup<16, 136, 241>(px, py, pz, d, o0, w0);
    level_setup<9, 69, 121>(px, py, pz, d, o1, w1);

    // Issue ALL 16 gathers, then fence the scheduler: nothing may cross, so
    // all 16 stay in flight (r7 evidence: without this, VGPR=36 => ~2 in
    // flight). Consume in issue order so vmcnt drains progressively.
    floatx4 v0[8], v1[8];
#pragma unroll
    for (int c = 0; c < 8; ++c) v0[c] = *(const floatx4*)(emb0 + o0[c]);
#pragma unroll
    for (int c = 0; c < 8; ++c) v1[c] = *(const floatx4*)(emb1 + o1[c]);
    __builtin_amdgcn_sched_barrier(0);

    floatx4 a0 = {0.f, 0.f, 0.f, 0.f}, a1 = {0.f, 0.f, 0.f, 0.f};
#pragma unroll
    for (int c = 0; c < 8; ++c) a0 += w0[c] * v0[c];
#pragma unroll
    for (int c = 0; c < 8; ++c) a1 += w1[c] * v1[c];

    __builtin_nontemporal_store(a0, (floatx4*)(row + d));
    __builtin_nontemporal_store(a1, (floatx4*)(row + 16 + d));
}

__global__ __launch_bounds__(256)
void k_main_sorted(const floatx4* __restrict__ sorted,
                   const float* __restrict__ emb0,
                   const float* __restrict__ emb1,
                   float* __restrict__ out, int n) {
    // bijective XCD swizzle (m204 form), NXCD=8
    const int nwg = gridDim.x;
    const int q = nwg >> 3, r = nwg & 7;
    const int xcd = blockIdx.x & 7, i = blockIdx.x >> 3;
    const int wg = (xcd < r ? xcd * (q + 1) : r * (q + 1) + (xcd - r) * q) + i;

    const int g = wg * blockDim.x + threadIdx.x;
    const int sp = g >> 2;
    const int d = (g & 3) * 4;
    if (sp >= n) return;

    const floatx4 pc = sorted[sp];
    const int orig = __float_as_int(pc.w);
    encode_point(pc.x, pc.y, pc.z, d, emb0, emb1, out + (size_t)orig * 32);
}

// fallback (no workspace)
__global__ __launch_bounds__(256)
void k_main_plain(const float* __restrict__ pts,
                  const float* __restrict__ emb0,
                  const float* __restrict__ emb1,
                  float* __restrict__ out, int n) {
    const int g = blockIdx.x * blockDim.x + threadIdx.x;
    const int p = g >> 2;
    const int d = (g & 3) * 4;
    if (p >= n) return;
    const size_t b = (size_t)p * 3;
    encode_point(pts[b], pts[b + 1], pts[b + 2], d, emb0, emb1,
                 out + (size_t)p * 32);
}

extern "C" void kernel_launch(void* const* d_in, const int* in_sizes, int n_in,
                              void* d_out, int out_size, void* d_ws, size_t ws_size,
                              hipStream_t stream) {
    const float* pts  = (const float*)d_in[0];
    const float* emb0 = (const float*)d_in[1];
    const float* emb1 = (const float*)d_in[2];
    float* out = (float*)d_out;
    const int n = in_sizes[0] / 3;

    const int block = 256;
    const int n4      = (n + 3) / 4;
    const int grid_p4 = (n4 + block - 1) / block;                       // 4 pts/thread
    const int grid_4l = (int)(((long long)n * 4 + block - 1) / block);  // 4 lanes/pt

    // workspace layout
    const size_t off_keys   = 0;
    const size_t off_rank   = off_keys + (size_t)n * 4;
    const size_t off_sorted = (off_rank + (size_t)n * 4 + 15) & ~(size_t)15;
    const size_t off_hist   = off_sorted + (size_t)n * 16;
    const size_t off_base   = off_hist + (size_t)NBINS * 4;
    const size_t need       = off_base + (size_t)NBINS * 4;

    if (ws_size < need) {
        k_main_plain<<<grid_4l, block, 0, stream>>>(pts, emb0, emb1, out, n);
        return;
    }

    char* ws = (char*)d_ws;
    unsigned* keys   = (unsigned*)(ws + off_keys);
    unsigned* rank   = (unsigned*)(ws + off_rank);
    floatx4*  sorted = (floatx4*)(ws + off_sorted);
    unsigned* hist   = (unsigned*)(ws + off_hist);
    unsigned* base   = (unsigned*)(ws + off_base);

    hipMemsetAsync(hist, 0, (size_t)NBINS * 4, stream);
    k_hist<<<grid_p4, block, 0, stream>>>(pts, n, keys, rank, hist);
    k_scan<<<1, SCAN_T, 0, stream>>>(hist, base);
    k_scatter<<<grid_p4, block, 0, stream>>>(pts, n, keys, rank, base, sorted);
    k_main_sorted<<<grid_4l, block, 0, stream>>>(sorted, emb0, emb1, out, n);
}